// Round 21
// baseline (123.356 us; speedup 1.0000x reference)
//
#include <hip/hip_runtime.h>

// NCC2D fused: 5 box-sums (9x9, zero-pad) + cc + global mean.
// R13 = R12's 1-wave/LDS-ring/prefetch shape + ONE change: 2 cols/lane
// (float2) -> 4 cols/lane (float4). Evidence: R7/R8/R11/R12 (all float2)
// converge at main 41-50us / 1.0-1.4 TB/s effective BW regardless of
// residency, barriers, or prefetch depth; R6 (the only float4 kernel)
// sustained 3.2 TB/s; fill kernels prove 6.4 TB/s available. dur tracks
// bytes/BW -> per-lane load WIDTH is the limiter (G13: 16B/lane sweet spot).
// Per 64-thread block (wave == workgroup), 256col x 16row output tile:
//   * 4 core cols/lane (float4) + 1 halo col on lanes 0..7.
//   * 9-row raw-row history in LDS ring (same-lane addr, program order).
//   * 3-deep register prefetch (30 floats; fits the ~88-VGPR grant that
//     R9 demonstrated for 1-wave loops -- R10's 110-float spill avoided).
//   * EMIT via per-block Vbuf, wave-level fences (near-free, R8/R12).
// Grid 2x32x32 = 2048 blocks; LDS 24.5KB -> ~6 resident/CU.
// d_ws: 2048 block partials (float). Kernel 2 reduces in double -> -mean.

#define BATCH     32
#define IMH       512
#define IMW       512
#define SH        16          // output rows per block
#define NROWSTRIP 32          // 512/16
#define NCOLSTRIP 2           // 512/256
#define CBW       256         // output cols per block
#define NK        (SH + 8)    // input rows per block (24 = 8*3)
#define VROW      264         // 4 halo + 256 + 4 halo
#define NPART     (BATCH * NROWSTRIP * NCOLSTRIP)   // 2048

// guarded prefetch of input row KK: 4 core cols (float4) + halo (lanes 0..7)
#define PREFG(KK, CI, CJ, HI, HJ) do {                                     \
    const int kk_ = (KK);                                                  \
    const int ri_ = r0 - 4 + kk_;                                          \
    CI = make_float4(0.f, 0.f, 0.f, 0.f);                                  \
    CJ = make_float4(0.f, 0.f, 0.f, 0.f);                                  \
    HI = 0.f; HJ = 0.f;                                                    \
    if (kk_ < NK && (unsigned)ri_ < (unsigned)IMH) {                       \
        const float* rI_ = Ib + (size_t)ri_ * IMW;                         \
        const float* rJ_ = Jb + (size_t)ri_ * IMW;                         \
        CI = *(const float4*)(rI_ + cc0);                                  \
        CJ = *(const float4*)(rJ_ + cc0);                                  \
        if (u < 8 && (unsigned)hc < (unsigned)IMW) {                       \
            HI = rI_[hc]; HJ = rJ_[hc];                                    \
        }                                                                  \
    }                                                                      \
} while (0)

// horizontal 9-window sums for the 4 owned cols from Vbuf row QI.
// window cols cc0-4..cc0+7 = Vbuf idx l0..l0+11 -> three float4 reads.
#define HWIN(QI, H0, H1, H2, H3) do {                                      \
    const float4 w0_ = *(const float4*)&Vbuf[QI][l0];                      \
    const float4 w1_ = *(const float4*)&Vbuf[QI][l0 + 4];                  \
    const float4 w2_ = *(const float4*)&Vbuf[QI][l0 + 8];                  \
    H0 = ((w0_.x + w0_.y) + (w0_.z + w0_.w))                               \
       + ((w1_.x + w1_.y) + (w1_.z + w1_.w)) + w2_.x;                      \
    H1 = H0 + w2_.y - w0_.x;                                               \
    H2 = H1 + w2_.z - w0_.y;                                               \
    H3 = H2 + w2_.w - w0_.z;                                               \
} while (0)

#define CC1(AI, AJ, S2, S3, S4) do {                                       \
    const float cross = (S4) - (AI)*(AJ)*inv81;                            \
    const float ivv   = (S2) - (AI)*(AI)*inv81;                            \
    const float jvv   = (S3) - (AJ)*(AJ)*inv81;                            \
    acc += cross * cross * __builtin_amdgcn_rcpf(ivv * jvv + 1e-5f);       \
} while (0)

// exchange V through Vbuf, horizontal 9-sums, accumulate cc (4 cols)
#define EMIT() do {                                                        \
    *(float4*)&Vbuf[0][4 + l0] = make_float4(VI0, VI1, VI2, VI3);          \
    *(float4*)&Vbuf[1][4 + l0] = make_float4(VJ0, VJ1, VJ2, VJ3);          \
    *(float4*)&Vbuf[2][4 + l0] = make_float4(VA0, VA1, VA2, VA3);          \
    *(float4*)&Vbuf[3][4 + l0] = make_float4(VB0, VB1, VB2, VB3);          \
    *(float4*)&Vbuf[4][4 + l0] = make_float4(VC0, VC1, VC2, VC3);          \
    if (u < 8) {                                                           \
        Vbuf[0][hx] = hVI; Vbuf[1][hx] = hVJ; Vbuf[2][hx] = hVA;           \
        Vbuf[3][hx] = hVB; Vbuf[4][hx] = hVC;                              \
    }                                                                      \
    __syncthreads();   /* 1-wave workgroup: near-free fence */             \
    float HI0, HI1, HI2, HI3, HJ0, HJ1, HJ2, HJ3;                          \
    float HA0, HA1, HA2, HA3, HB0, HB1, HB2, HB3;                          \
    float HC0, HC1, HC2, HC3;                                              \
    HWIN(0, HI0, HI1, HI2, HI3);                                           \
    HWIN(1, HJ0, HJ1, HJ2, HJ3);                                           \
    HWIN(2, HA0, HA1, HA2, HA3);                                           \
    HWIN(3, HB0, HB1, HB2, HB3);                                           \
    HWIN(4, HC0, HC1, HC2, HC3);                                           \
    CC1(HI0, HJ0, HA0, HB0, HC0);                                          \
    CC1(HI1, HJ1, HA1, HB1, HC1);                                          \
    CC1(HI2, HJ2, HA2, HB2, HC2);                                          \
    CC1(HI3, HJ3, HA3, HB3, HC3);                                          \
    __syncthreads();   /* WAR fence before next EMIT's writes */           \
} while (0)

// one row step: LDS-ring old/new (same lane addr -> program order),
// V update (4 core cols + halo col), emit when K>=8. K block-uniform.
#define BODY(K, CI, CJ, HI, HJ) do {                                       \
    float4 oi = make_float4(0.f, 0.f, 0.f, 0.f);                           \
    float4 oj = make_float4(0.f, 0.f, 0.f, 0.f);                           \
    float2 oh = make_float2(0.f, 0.f);                                     \
    if ((K) >= 9) {                                                        \
        oi = ringI[slot][u];                                               \
        oj = ringJ[slot][u];                                               \
        if (u < 8) oh = ringH[slot][u];                                    \
    }                                                                      \
    ringI[slot][u] = CI;                                                   \
    ringJ[slot][u] = CJ;                                                   \
    if (u < 8) ringH[slot][u] = make_float2(HI, HJ);                       \
    slot = (slot == 8) ? 0 : slot + 1;                                     \
    VI0 += CI.x - oi.x;           VI1 += CI.y - oi.y;                      \
    VI2 += CI.z - oi.z;           VI3 += CI.w - oi.w;                      \
    VJ0 += CJ.x - oj.x;           VJ1 += CJ.y - oj.y;                      \
    VJ2 += CJ.z - oj.z;           VJ3 += CJ.w - oj.w;                      \
    VA0 += CI.x*CI.x - oi.x*oi.x; VA1 += CI.y*CI.y - oi.y*oi.y;            \
    VA2 += CI.z*CI.z - oi.z*oi.z; VA3 += CI.w*CI.w - oi.w*oi.w;            \
    VB0 += CJ.x*CJ.x - oj.x*oj.x; VB1 += CJ.y*CJ.y - oj.y*oj.y;            \
    VB2 += CJ.z*CJ.z - oj.z*oj.z; VB3 += CJ.w*CJ.w - oj.w*oj.w;            \
    VC0 += CI.x*CJ.x - oi.x*oj.x; VC1 += CI.y*CJ.y - oi.y*oj.y;            \
    VC2 += CI.z*CJ.z - oi.z*oj.z; VC3 += CI.w*CJ.w - oi.w*oj.w;            \
    hVI += HI - oh.x;             hVJ += HJ - oh.y;                        \
    hVA += HI*HI - oh.x*oh.x;                                              \
    hVB += HJ*HJ - oh.y*oh.y;                                              \
    hVC += HI*HJ - oh.x*oh.y;                                              \
    if ((K) >= 8) { EMIT(); }                                              \
} while (0)

__global__ __launch_bounds__(64) void ncc_main(const float* __restrict__ I,
                                               const float* __restrict__ J,
                                               float* __restrict__ partial) {
    const int u    = threadIdx.x;        // 0..63
    const int cs   = blockIdx.x;         // col strip (0..1)
    const int s    = blockIdx.y;         // row strip (0..31)
    const int b    = blockIdx.z;         // image
    const int r0   = s * SH;
    const int cblk = cs * CBW;
    const int cc0  = cblk + 4 * u;       // first owned core col (abs, x4 -> 16B aligned)
    // halo col for lanes 0..7: 0-3 -> cblk-4..cblk-1, 4-7 -> cblk+256..259
    const int hc   = cblk + (u < 4 ? u - 4 : 252 + u);
    const int hx   = (u < 4) ? u : 256 + u;   // Vbuf idx of halo col
    const int l0   = 4 * u;              // HWIN base idx (col cc0-4)
    const float inv81 = 1.0f / 81.0f;

    const float* Ib = I + (size_t)b * IMH * IMW;
    const float* Jb = J + (size_t)b * IMH * IMW;

    __shared__ float4 ringI[9][64];      // 9.2 KB core I history
    __shared__ float4 ringJ[9][64];      // 9.2 KB core J history
    __shared__ float2 ringH[9][8];       // 576 B halo history (I,J)
    __shared__ float  Vbuf[5][VROW];     // 5.3 KB exchange buffer

    // zero the 8 pad cols (idx 0..3, 260..263) of each of the 5 Vbuf rows
    if (u < 40) {
        const int q = u >> 3, p = u & 7;
        Vbuf[q][p < 4 ? p : 256 + p] = 0.f;
    }
    __syncthreads();

    float VI0 = 0.f, VI1 = 0.f, VI2 = 0.f, VI3 = 0.f;
    float VJ0 = 0.f, VJ1 = 0.f, VJ2 = 0.f, VJ3 = 0.f;
    float VA0 = 0.f, VA1 = 0.f, VA2 = 0.f, VA3 = 0.f;
    float VB0 = 0.f, VB1 = 0.f, VB2 = 0.f, VB3 = 0.f;
    float VC0 = 0.f, VC1 = 0.f, VC2 = 0.f, VC3 = 0.f;
    float hVI = 0.f, hVJ = 0.f, hVA = 0.f, hVB = 0.f, hVC = 0.f;
    float acc = 0.f;
    int slot = 0;

    // 3 named prefetch slots (30 floats) -- the in-register pipeline
    float4 pa_i, pa_j, pb_i, pb_j, pc_i, pc_j;
    float  pa_hi, pa_hj, pb_hi, pb_hj, pc_hi, pc_hj;
    PREFG(0, pa_i, pa_j, pa_hi, pa_hj);
    PREFG(1, pb_i, pb_j, pb_hi, pb_hj);
    PREFG(2, pc_i, pc_j, pc_hi, pc_hj);

#pragma unroll 1
    for (int g = 0; g < NK / 3; ++g) {   // 24 rows = 8 groups x 3 steps
        const int K = 3 * g;
        BODY(K,     pa_i, pa_j, pa_hi, pa_hj);
        PREFG(K + 3, pa_i, pa_j, pa_hi, pa_hj);
        BODY(K + 1, pb_i, pb_j, pb_hi, pb_hj);
        PREFG(K + 4, pb_i, pb_j, pb_hi, pb_hj);
        BODY(K + 2, pc_i, pc_j, pc_hi, pc_hj);
        PREFG(K + 5, pc_i, pc_j, pc_hi, pc_hj);
    }

    // single-wave reduction; lane 0 writes the block partial
    float sum = acc;
#pragma unroll
    for (int off = 32; off > 0; off >>= 1) sum += __shfl_down(sum, off, 64);
    if (u == 0) {
        partial[((size_t)b * NROWSTRIP + s) * NCOLSTRIP + cs] = sum;
    }
}

__global__ __launch_bounds__(256) void ncc_reduce(const float* __restrict__ partial,
                                                  float* __restrict__ out) {
    const int t = threadIdx.x;
    double ssum = 0.0;
    for (int idx = t; idx < NPART; idx += 256) ssum += (double)partial[idx];
#pragma unroll
    for (int off = 32; off > 0; off >>= 1) ssum += __shfl_down(ssum, off, 64);

    __shared__ double wsum[4];
    if ((t & 63) == 0) wsum[t >> 6] = ssum;
    __syncthreads();
    if (t == 0) {
        const double total = wsum[0] + wsum[1] + wsum[2] + wsum[3];
        out[0] = (float)(-total / 8388608.0);  // -mean over 32*512*512
    }
}

extern "C" void kernel_launch(void* const* d_in, const int* in_sizes, int n_in,
                              void* d_out, int out_size, void* d_ws, size_t ws_size,
                              hipStream_t stream) {
    const float* I = (const float*)d_in[0];  // y_true
    const float* J = (const float*)d_in[1];  // y_pred
    float* partial = (float*)d_ws;           // NPART floats
    float* out     = (float*)d_out;

    dim3 grid(NCOLSTRIP, NROWSTRIP, BATCH);
    ncc_main<<<grid, 64, 0, stream>>>(I, J, partial);
    ncc_reduce<<<1, 256, 0, stream>>>(partial, out);
}

// Round 22
// 110.486 us; speedup vs baseline: 1.1165x; 1.1165x over previous
//
#include <hip/hip_runtime.h>

// NCC2D fused: 5 box-sums (9x9, zero-pad) + cc + global mean.
// R14: SHUFFLE-BASED HORIZONTAL SUMS, ZERO BARRIERS. R7-R13 converge at
// main 41-52us across float2/float4, 1/4-wave, 1/3/4-deep prefetch, 3 LDS
// sizes -- the shared invariant is the per-row Vbuf exchange (5 LDS writes
// -> fence -> 25 reads -> fence, ~550cy serialized x32 rows ~= the 40us
// floor). This kernel deletes it: ONE WAVE OWNS THE FULL 512-COL ROW
// (8 cols/lane = 2xfloat4/image), so horizontal 9-sums need only lane u-1's
// 4 suffix sums + lane u+1's 4 prefix sums per quantity = 40 __shfl + ~170
// VALU per emitted row, NO fences. Edge lanes predicate to zero (image
// zero-pad == block edge). Raw-row ring in LDS (same-lane addr, program
// order -- no fence). 2-deep register prefetch. launch_bounds(64,1):
// 1 wave/SIMD -> allocator can grant >100 VGPR (R5: 116 granted).
// Grid 32x32 = 1024 one-wave blocks; LDS 36.9KB -> 4 blocks/CU, one gen.
// d_ws: 1024 block partials (float). Kernel 2 reduces in double -> -mean.

#define BATCH     32
#define IMH       512
#define IMW       512
#define SH        16          // output rows per block
#define NROWSTRIP 32          // 512/16
#define NK        (SH + 8)    // input rows per block (24 = 12*2)
#define NPART     (BATCH * NROWSTRIP)   // 1024

// guarded prefetch of input row KK: 8 cols as 2 float4 per image
#define PREFG(KK, ILO, IHI, JLO, JHI) do {                                 \
    const int kk_ = (KK);                                                  \
    const int ri_ = r0 - 4 + kk_;                                          \
    ILO = z4; IHI = z4; JLO = z4; JHI = z4;                                \
    if (kk_ < NK && (unsigned)ri_ < (unsigned)IMH) {                       \
        const float* rI_ = Ib + (size_t)ri_ * IMW + c0;                    \
        const float* rJ_ = Jb + (size_t)ri_ * IMW + c0;                    \
        ILO = *(const float4*)(rI_);                                       \
        IHI = *(const float4*)(rI_ + 4);                                   \
        JLO = *(const float4*)(rJ_);                                       \
        JHI = *(const float4*)(rJ_ + 4);                                   \
    }                                                                      \
} while (0)

// horizontal 9-window sums for 8 cols from per-lane V (LO=c0..3, HI_=c4..7).
// Needs lane u-1's suffix sums (its c4..c7 tails) and u+1's prefixes.
#define HQ(LO, HI_, H0, H1, H2, H3, H4, H5, H6, H7) do {                   \
    const float P0 = (LO).x, P1 = P0 + (LO).y,                             \
                P2 = P1 + (LO).z, P3 = P2 + (LO).w;                        \
    const float P4 = P3 + (HI_).x, P5 = P4 + (HI_).y,                      \
                P6 = P5 + (HI_).z, P7 = P6 + (HI_).w;                      \
    const float S1 = (HI_).w, S2 = (HI_).z + S1,                           \
                S3 = (HI_).y + S2, S4 = (HI_).x + S3;                      \
    float ls4 = __shfl(S4, u - 1, 64), ls3 = __shfl(S3, u - 1, 64);        \
    float ls2 = __shfl(S2, u - 1, 64), ls1 = __shfl(S1, u - 1, 64);        \
    float rp1 = __shfl(P0, u + 1, 64), rp2 = __shfl(P1, u + 1, 64);        \
    float rp3 = __shfl(P2, u + 1, 64), rp4 = __shfl(P3, u + 1, 64);        \
    if (u == 0)  { ls4 = 0.f; ls3 = 0.f; ls2 = 0.f; ls1 = 0.f; }           \
    if (u == 63) { rp1 = 0.f; rp2 = 0.f; rp3 = 0.f; rp4 = 0.f; }           \
    H0 = ls4 + P4;        H1 = ls3 + P5;                                   \
    H2 = ls2 + P6;        H3 = ls1 + P7;                                   \
    H4 = P7 + rp1;        H5 = (P7 - P0) + rp2;                            \
    H6 = (P7 - P1) + rp3; H7 = (P7 - P2) + rp4;                            \
} while (0)

// componentwise V updates: V += N - O (and squared / product forms)
#define ADD4(V, N, O) do {                                                 \
    V.x += (N).x - (O).x; V.y += (N).y - (O).y;                            \
    V.z += (N).z - (O).z; V.w += (N).w - (O).w; } while (0)
#define ADDSQ4(V, N, O) do {                                               \
    V.x += (N).x*(N).x - (O).x*(O).x; V.y += (N).y*(N).y - (O).y*(O).y;    \
    V.z += (N).z*(N).z - (O).z*(O).z; V.w += (N).w*(N).w - (O).w*(O).w;    \
} while (0)
#define ADDPR4(V, NI, NJ, OI, OJ) do {                                     \
    V.x += (NI).x*(NJ).x - (OI).x*(OJ).x;                                  \
    V.y += (NI).y*(NJ).y - (OI).y*(OJ).y;                                  \
    V.z += (NI).z*(NJ).z - (OI).z*(OJ).z;                                  \
    V.w += (NI).w*(NJ).w - (OI).w*(OJ).w; } while (0)

#define CCK(CR, IV, JV)                                                    \
    acc += (CR) * (CR) * __builtin_amdgcn_rcpf((IV) * (JV) + 1e-5f)

// emit one output row: shuffle-based H for 5 quantities, staged to cap
// register liveness, then 8 cc accumulations. No LDS, no fences.
#define EMIT() do {                                                        \
    float hI0,hI1,hI2,hI3,hI4,hI5,hI6,hI7;                                 \
    float hJ0,hJ1,hJ2,hJ3,hJ4,hJ5,hJ6,hJ7;                                 \
    HQ(VIlo, VIhi, hI0,hI1,hI2,hI3,hI4,hI5,hI6,hI7);                       \
    HQ(VJlo, VJhi, hJ0,hJ1,hJ2,hJ3,hJ4,hJ5,hJ6,hJ7);                       \
    const float x10=hI0*hJ0*inv81, x11=hI1*hJ1*inv81, x12=hI2*hJ2*inv81,   \
                x13=hI3*hJ3*inv81, x14=hI4*hJ4*inv81, x15=hI5*hJ5*inv81,   \
                x16=hI6*hJ6*inv81, x17=hI7*hJ7*inv81;                      \
    const float x20=hI0*hI0*inv81, x21=hI1*hI1*inv81, x22=hI2*hI2*inv81,   \
                x23=hI3*hI3*inv81, x24=hI4*hI4*inv81, x25=hI5*hI5*inv81,   \
                x26=hI6*hI6*inv81, x27=hI7*hI7*inv81;                      \
    const float x30=hJ0*hJ0*inv81, x31=hJ1*hJ1*inv81, x32=hJ2*hJ2*inv81,   \
                x33=hJ3*hJ3*inv81, x34=hJ4*hJ4*inv81, x35=hJ5*hJ5*inv81,   \
                x36=hJ6*hJ6*inv81, x37=hJ7*hJ7*inv81;                      \
    float hA0,hA1,hA2,hA3,hA4,hA5,hA6,hA7;                                 \
    HQ(VAlo, VAhi, hA0,hA1,hA2,hA3,hA4,hA5,hA6,hA7);                       \
    const float iv0=hA0-x20, iv1=hA1-x21, iv2=hA2-x22, iv3=hA3-x23;        \
    const float iv4=hA4-x24, iv5=hA5-x25, iv6=hA6-x26, iv7=hA7-x27;        \
    float hB0,hB1,hB2,hB3,hB4,hB5,hB6,hB7;                                 \
    HQ(VBlo, VBhi, hB0,hB1,hB2,hB3,hB4,hB5,hB6,hB7);                       \
    const float jv0=hB0-x30, jv1=hB1-x31, jv2=hB2-x32, jv3=hB3-x33;        \
    const float jv4=hB4-x34, jv5=hB5-x35, jv6=hB6-x36, jv7=hB7-x37;        \
    float hC0,hC1,hC2,hC3,hC4,hC5,hC6,hC7;                                 \
    HQ(VClo, VChi, hC0,hC1,hC2,hC3,hC4,hC5,hC6,hC7);                       \
    CCK(hC0-x10, iv0, jv0); CCK(hC1-x11, iv1, jv1);                        \
    CCK(hC2-x12, iv2, jv2); CCK(hC3-x13, iv3, jv3);                        \
    CCK(hC4-x14, iv4, jv4); CCK(hC5-x15, iv5, jv5);                        \
    CCK(hC6-x16, iv6, jv6); CCK(hC7-x17, iv7, jv7);                        \
} while (0)

// one row step: LDS-ring old/new (same lane addr -> program order, no
// fence), V updates for 8 cols, emit when K>=8. K block-uniform.
#define BODY(K, ILO, IHI, JLO, JHI) do {                                   \
    float4 oIlo = z4, oIhi = z4, oJlo = z4, oJhi = z4;                     \
    if ((K) >= 9) {                                                        \
        oIlo = ringI[slot][u][0]; oIhi = ringI[slot][u][1];                \
        oJlo = ringJ[slot][u][0]; oJhi = ringJ[slot][u][1];                \
    }                                                                      \
    ringI[slot][u][0] = ILO; ringI[slot][u][1] = IHI;                      \
    ringJ[slot][u][0] = JLO; ringJ[slot][u][1] = JHI;                      \
    slot = (slot == 8) ? 0 : slot + 1;                                     \
    ADD4(VIlo, ILO, oIlo);          ADD4(VIhi, IHI, oIhi);                 \
    ADD4(VJlo, JLO, oJlo);          ADD4(VJhi, JHI, oJhi);                 \
    ADDSQ4(VAlo, ILO, oIlo);        ADDSQ4(VAhi, IHI, oIhi);               \
    ADDSQ4(VBlo, JLO, oJlo);        ADDSQ4(VBhi, JHI, oJhi);               \
    ADDPR4(VClo, ILO, JLO, oIlo, oJlo);                                    \
    ADDPR4(VChi, IHI, JHI, oIhi, oJhi);                                    \
    if ((K) >= 8) { EMIT(); }                                              \
} while (0)

__global__ __launch_bounds__(64, 1) void ncc_main(const float* __restrict__ I,
                                                  const float* __restrict__ J,
                                                  float* __restrict__ partial) {
    const int u  = threadIdx.x;          // 0..63
    const int s  = blockIdx.x;           // row strip (0..31)
    const int b  = blockIdx.y;           // image
    const int r0 = s * SH;
    const int c0 = 8 * u;                // first owned col (8 cols/lane)
    const float inv81 = 1.0f / 81.0f;
    const float4 z4 = make_float4(0.f, 0.f, 0.f, 0.f);

    const float* Ib = I + (size_t)b * IMH * IMW;
    const float* Jb = J + (size_t)b * IMH * IMW;

    __shared__ float4 ringI[9][64][2];   // 18.4 KB raw I history
    __shared__ float4 ringJ[9][64][2];   // 18.4 KB raw J history

    // vertical 9-row running sums: 5 quantities x 8 cols (10 float4)
    float4 VIlo = z4, VIhi = z4, VJlo = z4, VJhi = z4;
    float4 VAlo = z4, VAhi = z4, VBlo = z4, VBhi = z4;
    float4 VClo = z4, VChi = z4;
    float acc = 0.f;
    int slot = 0;

    // 2 named prefetch slots (32 floats) -- the in-register pipeline
    float4 aIlo, aIhi, aJlo, aJhi, bIlo, bIhi, bJlo, bJhi;
    PREFG(0, aIlo, aIhi, aJlo, aJhi);
    PREFG(1, bIlo, bIhi, bJlo, bJhi);

#pragma unroll 1
    for (int g = 0; g < NK / 2; ++g) {   // 24 rows = 12 groups x 2 steps
        const int K = 2 * g;
        BODY(K,     aIlo, aIhi, aJlo, aJhi);
        PREFG(K + 2, aIlo, aIhi, aJlo, aJhi);
        BODY(K + 1, bIlo, bIhi, bJlo, bJhi);
        PREFG(K + 3, bIlo, bIhi, bJlo, bJhi);
    }

    // single-wave reduction; lane 0 writes the block partial
    float sum = acc;
#pragma unroll
    for (int off = 32; off > 0; off >>= 1) sum += __shfl_down(sum, off, 64);
    if (u == 0) {
        partial[(size_t)b * NROWSTRIP + s] = sum;
    }
}

__global__ __launch_bounds__(256) void ncc_reduce(const float* __restrict__ partial,
                                                  float* __restrict__ out) {
    const int t = threadIdx.x;
    double ssum = 0.0;
    for (int idx = t; idx < NPART; idx += 256) ssum += (double)partial[idx];
#pragma unroll
    for (int off = 32; off > 0; off >>= 1) ssum += __shfl_down(ssum, off, 64);

    __shared__ double wsum[4];
    if ((t & 63) == 0) wsum[t >> 6] = ssum;
    __syncthreads();
    if (t == 0) {
        const double total = wsum[0] + wsum[1] + wsum[2] + wsum[3];
        out[0] = (float)(-total / 8388608.0);  // -mean over 32*512*512
    }
}

extern "C" void kernel_launch(void* const* d_in, const int* in_sizes, int n_in,
                              void* d_out, int out_size, void* d_ws, size_t ws_size,
                              hipStream_t stream) {
    const float* I = (const float*)d_in[0];  // y_true
    const float* J = (const float*)d_in[1];  // y_pred
    float* partial = (float*)d_ws;           // NPART floats
    float* out     = (float*)d_out;

    dim3 grid(NROWSTRIP, BATCH);
    ncc_main<<<grid, 64, 0, stream>>>(I, J, partial);
    ncc_reduce<<<1, 256, 0, stream>>>(partial, out);
}